// Round 8
// baseline (87.759 us; speedup 1.0000x reference)
//
#include <hip/hip_runtime.h>

typedef __attribute__((ext_vector_type(8))) short short8v;
typedef __attribute__((ext_vector_type(4))) float float4v;
typedef unsigned int uint;

#define TWO_LOG2E 2.8853900817779268f   // 2*log2(e)
#define LOG2E     1.4426950408889634f

// ---------------------------------------------------------------------------
// f32 -> bf16 helpers (RNE), packing pairs into uint words
// ---------------------------------------------------------------------------
__device__ inline uint rne_bf16(float x) {
    uint u = __float_as_uint(x);
    return (u + 0x7fffu + ((u >> 16) & 1u)) >> 16;
}
__device__ inline uint pack_hi_lo(float a0, float a1, uint& lo_pack) {
    const uint h0 = rne_bf16(a0), h1 = rne_bf16(a1);
    const float f0 = __uint_as_float(h0 << 16), f1 = __uint_as_float(h1 << 16);
    const float l0 = a0 - f0, l1 = a1 - f1;
    lo_pack = (rne_bf16(l1) << 16) | rne_bf16(l0);
    return (h1 << 16) | h0;
}

// ---------------------------------------------------------------------------
// prep_a: split A = [query(1024 rows); key(4096 rows)] x 512 into bf16 hi/lo.
// ---------------------------------------------------------------------------
__global__ __launch_bounds__(256) void prep_a(
    const float* __restrict__ query, const float* __restrict__ key,
    const int* __restrict__ vlen,
    ushort* __restrict__ A_hi, ushort* __restrict__ A_lo)
{
    const int t = blockIdx.x * 256 + threadIdx.x;   // 327680 total
    const int row = t >> 6;
    const int cg = (t & 63) * 8;
    if (row >= 1024) {
        const int kr = (row - 1024) & 1023, b = (row - 1024) >> 10;
        if ((kr & ~63) >= vlen[b]) return;
    }
    const float* src = (row < 1024) ? (query + (size_t)row * 512 + cg)
                                    : (key + (size_t)(row - 1024) * 512 + cg);
    const float4 x0 = *(const float4*)src;
    const float4 x1 = *(const float4*)(src + 4);
    uint h0, h1, h2, h3, l0, l1, l2, l3;
    h0 = pack_hi_lo(x0.x, x0.y, l0);
    h1 = pack_hi_lo(x0.z, x0.w, l1);
    h2 = pack_hi_lo(x1.x, x1.y, l2);
    h3 = pack_hi_lo(x1.z, x1.w, l3);
    *(uint4*)(A_hi + (size_t)row * 512 + cg) = make_uint4(h0, h1, h2, h3);
    *(uint4*)(A_lo + (size_t)row * 512 + cg) = make_uint4(l0, l1, l2, l3);
}

// ---------------------------------------------------------------------------
// prep_w: WT_hi/lo[w][n][k] = split(W_w[k][n]) — transpose + hi/lo split.
// ---------------------------------------------------------------------------
__global__ __launch_bounds__(256) void prep_w(
    const float* __restrict__ Wq, const float* __restrict__ Wk,
    ushort* __restrict__ WT_hi, ushort* __restrict__ WT_lo)
{
    const int t = blockIdx.x * 256 + threadIdx.x;   // 32768 total
    const int n = t & 255;
    const int kg = ((t >> 8) & 63) * 8;
    const int w = t >> 14;
    const float* W = w ? Wk : Wq;
    float x[8];
    #pragma unroll
    for (int i = 0; i < 8; ++i) x[i] = W[(size_t)(kg + i) * 256 + n];
    uint h0, h1, h2, h3, l0, l1, l2, l3;
    h0 = pack_hi_lo(x[0], x[1], l0);
    h1 = pack_hi_lo(x[2], x[3], l1);
    h2 = pack_hi_lo(x[4], x[5], l2);
    h3 = pack_hi_lo(x[6], x[7], l3);
    const size_t off = ((size_t)w * 256 + n) * 512 + kg;
    *(uint4*)(WT_hi + off) = make_uint4(h0, h1, h2, h3);
    *(uint4*)(WT_lo + off) = make_uint4(l0, l1, l2, l3);
}

// ---------------------------------------------------------------------------
// prep_v: VT_hi/lo[b][n][k] = split(value[b][k][n]) — LDS 64x64 transpose.
// ---------------------------------------------------------------------------
__global__ __launch_bounds__(256) void prep_v(
    const float* __restrict__ value, const int* __restrict__ vlen,
    ushort* __restrict__ VT_hi, ushort* __restrict__ VT_lo)
{
    __shared__ float t[64][69];
    const int b = blockIdx.z;
    const int k0 = blockIdx.y * 64, n0 = blockIdx.x * 64;
    const int kendB = (vlen[b] + 31) & ~31;
    if (k0 >= kendB) return;

    const int tid = threadIdx.x;
    const int n_in = (tid & 15) * 4, k_in = tid >> 4;
    const float* src = value + ((size_t)b * 1024 + k0 + k_in) * 512 + n0 + n_in;
    #pragma unroll
    for (int p = 0; p < 4; ++p) {
        const float4 x = *(const float4*)(src + (size_t)p * 16 * 512);
        t[k_in + p * 16][n_in + 0] = x.x;
        t[k_in + p * 16][n_in + 1] = x.y;
        t[k_in + p * 16][n_in + 2] = x.z;
        t[k_in + p * 16][n_in + 3] = x.w;
    }
    __syncthreads();

    const int rn = tid >> 2, c0 = (tid & 3) * 16;
    uint hp[8], lp[8];
    #pragma unroll
    for (int i = 0; i < 8; ++i)
        hp[i] = pack_hi_lo(t[c0 + 2 * i][rn], t[c0 + 2 * i + 1][rn], lp[i]);
    const size_t off = ((size_t)b * 512 + n0 + rn) * 1024 + k0 + c0;
    *(uint4*)(VT_hi + off) = make_uint4(hp[0], hp[1], hp[2], hp[3]);
    *(uint4*)(VT_hi + off + 8) = make_uint4(hp[4], hp[5], hp[6], hp[7]);
    *(uint4*)(VT_lo + off) = make_uint4(lp[0], lp[1], lp[2], lp[3]);
    *(uint4*)(VT_lo + off + 8) = make_uint4(lp[4], lp[5], lp[6], lp[7]);
}

// ---------------------------------------------------------------------------
// Kernel P (MFMA): proj via 3-MFMA hi/lo bf16 split. Wave tile 32m x 64n,
// K=512 by 32, register double-buffered.
// ---------------------------------------------------------------------------
#define LOADF(s, kbase) { const int ko = (kbase) + half * 8;                \
    _Pragma("unroll") for (int f = 0; f < 2; ++f) {                         \
        ah##s[f] = *(const short8v*)(a_h + (size_t)(f * 16) * 512 + ko);    \
        al##s[f] = *(const short8v*)(a_l + (size_t)(f * 16) * 512 + ko); }  \
    _Pragma("unroll") for (int f = 0; f < 4; ++f) {                         \
        bh##s[f] = *(const short8v*)(wt_h + (size_t)(f * 16) * 512 + ko);   \
        bl##s[f] = *(const short8v*)(wt_l + (size_t)(f * 16) * 512 + ko); } }

#define MFMAS(s)                                                                          \
    _Pragma("unroll") for (int mf = 0; mf < 2; ++mf)                                      \
    _Pragma("unroll") for (int nf = 0; nf < 4; ++nf) {                                    \
        acc[mf][nf] = __builtin_amdgcn_mfma_f32_16x16x32_bf16(ah##s[mf], bh##s[nf], acc[mf][nf], 0, 0, 0); \
        acc[mf][nf] = __builtin_amdgcn_mfma_f32_16x16x32_bf16(ah##s[mf], bl##s[nf], acc[mf][nf], 0, 0, 0); \
        acc[mf][nf] = __builtin_amdgcn_mfma_f32_16x16x32_bf16(al##s[mf], bh##s[nf], acc[mf][nf], 0, 0, 0); }

__global__ __launch_bounds__(64) void proj_mfma(
    const ushort* __restrict__ A_hi, const ushort* __restrict__ A_lo,
    const ushort* __restrict__ WT_hi, const ushort* __restrict__ WT_lo,
    const int* __restrict__ valid_len,
    float* __restrict__ EqT, float* __restrict__ EkT)
{
    const int lane = threadIdx.x;
    const int n0 = blockIdx.x * 64;
    const int m0 = blockIdx.y * 32;
    const bool isq = (m0 < 1024);
    int b = 0, kk0 = 0;
    if (!isq) {
        kk0 = (m0 - 1024) & 1023;
        b = (m0 - 1024) >> 10;
        if (kk0 >= valid_len[b]) return;
    }
    const int r = lane & 15, half = lane >> 4;
    const size_t wsel = isq ? 0 : (size_t)256 * 512;
    const ushort* wt_h = WT_hi + wsel + (size_t)(n0 + r) * 512;
    const ushort* wt_l = WT_lo + wsel + (size_t)(n0 + r) * 512;
    const ushort* a_h = A_hi + (size_t)(m0 + r) * 512;
    const ushort* a_l = A_lo + (size_t)(m0 + r) * 512;

    float4v acc[2][4] = {{{0.f}}};
    short8v ah0[2], al0[2], bh0[4], bl0[4];
    short8v ah1[2], al1[2], bh1[4], bl1[4];

    LOADF(0, 0);
    for (int kt = 0; kt < 512; kt += 64) {
        LOADF(1, kt + 32);
        MFMAS(0);
        if (kt + 64 < 512) LOADF(0, kt + 64);
        MFMAS(1);
    }

    #pragma unroll
    for (int mf = 0; mf < 2; ++mf) {
        #pragma unroll
        for (int nf = 0; nf < 4; ++nf) {
            float4v e;
            #pragma unroll
            for (int i = 0; i < 4; ++i)
                e[i] = __builtin_amdgcn_exp2f(acc[mf][nf][i] * TWO_LOG2E);
            if (isq) {
                *(float4v*)(EqT + (size_t)(n0 + nf * 16 + r) * 1024 +
                            m0 + mf * 16 + half * 4) = e;
            } else {
                *(float4v*)(EkT + (size_t)(b * 256 + n0 + nf * 16 + r) * 1024 +
                            kk0 + mf * 16 + half * 4) = e;
            }
        }
    }
}

// ---------------------------------------------------------------------------
// Score pass A: P[hq][b*256+q][k] = sum_{h in quarter} wv[h]*rcp(Eq*Ek+1).
// Grid 2048 = (4 hq) x (4 k-tiles) x (32 q-tiles) x (4 b); 256 thr (4 waves).
// Per-thread work = 8q x 64h = 512 rcp -> ~4096 alive waves = 4/SIMD, with
// 2x block oversubscription so vlen-dead blocks drain and backfill (R6 fix).
// ---------------------------------------------------------------------------
__global__ __launch_bounds__(256) void score_partial(
    const float* __restrict__ EqT, const float* __restrict__ EkT,
    const float* __restrict__ wv, const int* __restrict__ valid_len,
    float* __restrict__ P)
{
    __shared__ float eqs[64][8];
    __shared__ float wvs[64];

    const int idx = blockIdx.x;
    const int hq = idx & 3;
    const int kt = (idx >> 2) & 3;
    const int qg = (idx >> 4) & 31;
    const int b  = idx >> 9;

    const int vlen = valid_len[b];
    if (kt * 256 >= vlen) return;                 // block-uniform dead exit

    const int tid = threadIdx.x;
    const int k = kt * 256 + tid;
    const int q0 = qg * 8;
    const int h0 = hq * 64;

    if (tid < 64) wvs[tid] = wv[h0 + tid];
    #pragma unroll
    for (int r = 0; r < 2; ++r) {
        const int i = r * 256 + tid;
        const int h = i >> 3, q = i & 7;
        eqs[h][q] = EqT[(size_t)(h0 + h) * 1024 + b * 256 + q0 + q];
    }
    __syncthreads();

    float acc[8] = {};
    if (k < vlen) {
        const float* ekp = EkT + (size_t)(b * 256 + h0) * 1024 + k;
        #pragma unroll 2
        for (int h = 0; h < 64; ++h) {
            const float ek = ekp[(size_t)h * 1024];
            const float w = wvs[h];
            const float4 e0 = *(const float4*)&eqs[h][0];
            const float4 e1 = *(const float4*)&eqs[h][4];
            acc[0] = fmaf(w, __builtin_amdgcn_rcpf(fmaf(e0.x, ek, 1.f)), acc[0]);
            acc[1] = fmaf(w, __builtin_amdgcn_rcpf(fmaf(e0.y, ek, 1.f)), acc[1]);
            acc[2] = fmaf(w, __builtin_amdgcn_rcpf(fmaf(e0.z, ek, 1.f)), acc[2]);
            acc[3] = fmaf(w, __builtin_amdgcn_rcpf(fmaf(e0.w, ek, 1.f)), acc[3]);
            acc[4] = fmaf(w, __builtin_amdgcn_rcpf(fmaf(e1.x, ek, 1.f)), acc[4]);
            acc[5] = fmaf(w, __builtin_amdgcn_rcpf(fmaf(e1.y, ek, 1.f)), acc[5]);
            acc[6] = fmaf(w, __builtin_amdgcn_rcpf(fmaf(e1.z, ek, 1.f)), acc[6]);
            acc[7] = fmaf(w, __builtin_amdgcn_rcpf(fmaf(e1.w, ek, 1.f)), acc[7]);
        }
    }

    float* Pq = P + (size_t)hq * 1048576;
    #pragma unroll
    for (int qi = 0; qi < 8; ++qi)
        Pq[(size_t)(b * 256 + q0 + qi) * 1024 + k] = acc[qi];
}

// ---------------------------------------------------------------------------
// Score pass B: masked softmax over s = -2*(P0+P1+P2+P3); bf16 hi/lo output.
// Block = (b, 4q); 1024 threads; thread owns k = tid.
// ---------------------------------------------------------------------------
__global__ __launch_bounds__(1024) void softmax_kernel(
    const float* __restrict__ P, const int* __restrict__ valid_len,
    ushort* __restrict__ attn_hi, ushort* __restrict__ attn_lo)
{
    __shared__ float red[16][4];

    const int tid = threadIdx.x;
    const int b = blockIdx.x >> 6;
    const int q0 = (blockIdx.x & 63) << 2;

    const int vlen = valid_len[b];
    const int k = tid;
    const bool v = (k < vlen);

    float s[4], m[4];
    #pragma unroll
    for (int q = 0; q < 4; ++q) {
        const size_t off = (size_t)(b * 256 + q0 + q) * 1024 + k;
        s[q] = -2.f * (P[off] + P[off + 1048576] +
                       P[off + 2097152] + P[off + 3145728]);
        m[q] = v ? s[q] : -1e30f;
    }
    #pragma unroll
    for (int o = 32; o; o >>= 1) {
        #pragma unroll
        for (int q = 0; q < 4; ++q) m[q] = fmaxf(m[q], __shfl_xor(m[q], o));
    }
    const int wid = tid >> 6;
    if ((tid & 63) == 0) {
        #pragma unroll
        for (int q = 0; q < 4; ++q) red[wid][q] = m[q];
    }
    __syncthreads();
    #pragma unroll
    for (int q = 0; q < 4; ++q) {
        float mm = red[0][q];
        #pragma unroll
        for (int w = 1; w < 16; ++w) mm = fmaxf(mm, red[w][q]);
        m[q] = mm;
    }
    __syncthreads();

    float p[4], l[4];
    #pragma unroll
    for (int q = 0; q < 4; ++q) {
        p[q] = v ? __builtin_amdgcn_exp2f((s[q] - m[q]) * LOG2E) : 0.f;
        l[q] = p[q];
    }
    #pragma unroll
    for (int o = 32; o; o >>= 1) {
        #pragma unroll
        for (int q = 0; q < 4; ++q) l[q] += __shfl_xor(l[q], o);
    }
    if ((tid & 63) == 0) {
        #pragma unroll
        for (int q = 0; q < 4; ++q) red[wid][q] = l[q];
    }
    __syncthreads();
    #pragma unroll
    for (int q = 0; q < 4; ++q) {
        float ss = red[0][q];
        #pragma unroll
        for (int w = 1; w < 16; ++w) ss += red[w][q];
        const float a = p[q] * __builtin_amdgcn_rcpf(ss);
        const uint hi = rne_bf16(a);
        const float lo = a - __uint_as_float(hi << 16);
        const size_t off = (size_t)(b * 256 + q0 + q) * 1024 + k;
        attn_hi[off] = (ushort)hi;
        attn_lo[off] = (ushort)rne_bf16(lo);
    }
}

// ---------------------------------------------------------------------------
// Kernel D (MFMA): out[b] = attn[b] @ value[b] via 3-MFMA hi/lo bf16.
// 1 wave per block, wave tile 16q x 32n, K bounded by ceil(vlen/32).
// ---------------------------------------------------------------------------
#define PVLOAD(s, ko) {                                   \
    ah##s = *(const short8v*)(ah_p + (ko));               \
    al##s = *(const short8v*)(al_p + (ko));               \
    bh0##s = *(const short8v*)(bh_p + (ko));              \
    bl0##s = *(const short8v*)(bl_p + (ko));              \
    bh1##s = *(const short8v*)(bh_p + 16 * 1024 + (ko));  \
    bl1##s = *(const short8v*)(bl_p + 16 * 1024 + (ko)); }

#define PVMFMA(s) {                                                              \
    acc0 = __builtin_amdgcn_mfma_f32_16x16x32_bf16(ah##s, bh0##s, acc0, 0, 0, 0); \
    acc0 = __builtin_amdgcn_mfma_f32_16x16x32_bf16(ah##s, bl0##s, acc0, 0, 0, 0); \
    acc0 = __builtin_amdgcn_mfma_f32_16x16x32_bf16(al##s, bh0##s, acc0, 0, 0, 0); \
    acc1 = __builtin_amdgcn_mfma_f32_16x16x32_bf16(ah##s, bh1##s, acc1, 0, 0, 0); \
    acc1 = __builtin_amdgcn_mfma_f32_16x16x32_bf16(ah##s, bl1##s, acc1, 0, 0, 0); \
    acc1 = __builtin_amdgcn_mfma_f32_16x16x32_bf16(al##s, bh1##s, acc1, 0, 0, 0); }

__global__ __launch_bounds__(64) void pv_mfma(
    const ushort* __restrict__ attn_hi, const ushort* __restrict__ attn_lo,
    const ushort* __restrict__ VT_hi, const ushort* __restrict__ VT_lo,
    const int* __restrict__ valid_len,
    float* __restrict__ out)
{
    const int lane = threadIdx.x;
    const int n0 = blockIdx.x * 32;
    const int q0 = blockIdx.y * 16;
    const int b = blockIdx.z;
    const int r = lane & 15, half = lane >> 4;
    const int kend = (valid_len[b] + 31) & ~31;

    const ushort* ah_p = attn_hi + (size_t)(b * 256 + q0 + r) * 1024 + half * 8;
    const ushort* al_p = attn_lo + (size_t)(b * 256 + q0 + r) * 1024 + half * 8;
    const ushort* bh_p = VT_hi + (size_t)(b * 512 + n0 + r) * 1024 + half * 8;
    const ushort* bl_p = VT_lo + (size_t)(b * 512 + n0 + r) * 1024 + half * 8;

    float4v acc0 = {0.f}, acc1 = {0.f};
    short8v ah0, al0, bh00, bl00, bh10, bl10;
    short8v ah1, al1, bh01, bl01, bh11, bl11;

    PVLOAD(0, 0);
    for (int kt = 0; kt < kend; kt += 64) {
        if (kt + 32 < kend) PVLOAD(1, kt + 32);
        PVMFMA(0);
        if (kt + 64 < kend) PVLOAD(0, kt + 64);
        if (kt + 32 < kend) PVMFMA(1);
    }

    float* op = out + (size_t)b * 256 * 512 + (size_t)(q0 + half * 4) * 512 + n0 + r;
    #pragma unroll
    for (int i = 0; i < 4; ++i) {
        op[(size_t)i * 512] = acc0[i];
        op[(size_t)i * 512 + 16] = acc1[i];
    }
}

// ---------------------------------------------------------------------------
extern "C" void kernel_launch(void* const* d_in, const int* in_sizes, int n_in,
                              void* d_out, int out_size, void* d_ws, size_t ws_size,
                              hipStream_t stream)
{
    const float* query = (const float*)d_in[0];   // [4,256,512]
    const float* key   = (const float*)d_in[1];   // [4,1024,512]
    const float* value = (const float*)d_in[2];   // [4,1024,512]
    const int*   vlen  = (const int*)d_in[3];     // [4]
    const float* Wq    = (const float*)d_in[4];   // [512,256]
    const float* Wk    = (const float*)d_in[5];   // [512,256]
    const float* wv    = (const float*)d_in[6];   // [256]
    float* out = (float*)d_out;                   // [4,256,512]

    float*  EqT     = (float*)d_ws;               // [256][1024]    = 262144 f
    float*  EkT     = EqT + 262144;               // [4][256][1024] = 1048576 f
    float*  P       = EkT + 1048576;              // [4][1024][1024]= 4194304 f
    ushort* A_hi    = (ushort*)(P + 4194304);     // [5120][512]
    ushort* A_lo    = A_hi + 2621440;
    ushort* WT_hi   = A_lo + 2621440;             // [2][256][512]
    ushort* WT_lo   = WT_hi + 262144;
    ushort* attn_hi = WT_lo + 262144;             // [1024][1024]
    ushort* attn_lo = attn_hi + 1048576;
    ushort* VT_hi   = attn_lo + 1048576;          // [4][512][1024]
    ushort* VT_lo   = VT_hi + 2097152;

    hipLaunchKernelGGL(prep_w, dim3(128), dim3(256), 0, stream,
                       Wq, Wk, WT_hi, WT_lo);
    hipLaunchKernelGGL(prep_a, dim3(1280), dim3(256), 0, stream,
                       query, key, vlen, A_hi, A_lo);
    hipLaunchKernelGGL(prep_v, dim3(8, 16, 4), dim3(256), 0, stream,
                       value, vlen, VT_hi, VT_lo);
    hipLaunchKernelGGL(proj_mfma, dim3(4, 160), dim3(64), 0, stream,
                       A_hi, A_lo, WT_hi, WT_lo, vlen, EqT, EkT);
    hipLaunchKernelGGL(score_partial, dim3(2048), dim3(256), 0, stream,
                       EqT, EkT, wv, vlen, P);
    hipLaunchKernelGGL(softmax_kernel, dim3(256), dim3(1024), 0, stream,
                       P, vlen, attn_hi, attn_lo);
    hipLaunchKernelGGL(pv_mfma, dim3(16, 16, 4), dim3(64), 0, stream,
                       attn_hi, attn_lo, VT_hi, VT_lo, vlen, out);
}

// Round 9
// 86.016 us; speedup vs baseline: 1.0203x; 1.0203x over previous
//
#include <hip/hip_runtime.h>

typedef __attribute__((ext_vector_type(8))) short short8v;
typedef __attribute__((ext_vector_type(4))) float float4v;
typedef unsigned int uint;

#define TWO_LOG2E 2.8853900817779268f   // 2*log2(e)
#define LOG2E     1.4426950408889634f

// ---------------------------------------------------------------------------
// f32 -> bf16 helpers
// ---------------------------------------------------------------------------
__device__ inline uint rne_bf16(float x) {
    uint u = __float_as_uint(x);
    return (u + 0x7fffu + ((u >> 16) & 1u)) >> 16;
}
__device__ inline uint pack_hi_lo(float a0, float a1, uint& lo_pack) {
    const uint h0 = rne_bf16(a0), h1 = rne_bf16(a1);
    const float f0 = __uint_as_float(h0 << 16), f1 = __uint_as_float(h1 << 16);
    const float l0 = a0 - f0, l1 = a1 - f1;
    lo_pack = (rne_bf16(l1) << 16) | rne_bf16(l0);
    return (h1 << 16) | h0;
}
// trunc-hi split of 8 f32 into bf16 hi/lo fragments (cheap in-kernel path)
__device__ inline void split8(const float4 x0, const float4 x1,
                              short8v& h, short8v& l) {
    const float xs[8] = {x0.x, x0.y, x0.z, x0.w, x1.x, x1.y, x1.z, x1.w};
    #pragma unroll
    for (int j = 0; j < 8; ++j) {
        const uint u = __float_as_uint(xs[j]);
        const uint hi = u & 0xFFFF0000u;
        const float lo = xs[j] - __uint_as_float(hi);
        h[j] = (short)(hi >> 16);
        l[j] = (short)rne_bf16(lo);
    }
}

// ---------------------------------------------------------------------------
// prep_w: WT_hi/lo[w][n][k] = split(W_w[k][n]) — transpose + hi/lo split.
// ---------------------------------------------------------------------------
__global__ __launch_bounds__(256) void prep_w(
    const float* __restrict__ Wq, const float* __restrict__ Wk,
    ushort* __restrict__ WT_hi, ushort* __restrict__ WT_lo)
{
    const int t = blockIdx.x * 256 + threadIdx.x;   // 32768 total
    const int n = t & 255;
    const int kg = ((t >> 8) & 63) * 8;
    const int w = t >> 14;
    const float* W = w ? Wk : Wq;
    float x[8];
    #pragma unroll
    for (int i = 0; i < 8; ++i) x[i] = W[(size_t)(kg + i) * 256 + n];
    uint h0, h1, h2, h3, l0, l1, l2, l3;
    h0 = pack_hi_lo(x[0], x[1], l0);
    h1 = pack_hi_lo(x[2], x[3], l1);
    h2 = pack_hi_lo(x[4], x[5], l2);
    h3 = pack_hi_lo(x[6], x[7], l3);
    const size_t off = ((size_t)w * 256 + n) * 512 + kg;
    *(uint4*)(WT_hi + off) = make_uint4(h0, h1, h2, h3);
    *(uint4*)(WT_lo + off) = make_uint4(l0, l1, l2, l3);
}

// ---------------------------------------------------------------------------
// prep_v: VT_hi/lo[b][n][k] = split(value[b][k][n]) — LDS 64x64 transpose.
// ---------------------------------------------------------------------------
__global__ __launch_bounds__(256) void prep_v(
    const float* __restrict__ value, const int* __restrict__ vlen,
    ushort* __restrict__ VT_hi, ushort* __restrict__ VT_lo)
{
    __shared__ float t[64][69];
    const int b = blockIdx.z;
    const int k0 = blockIdx.y * 64, n0 = blockIdx.x * 64;
    const int kendB = (vlen[b] + 31) & ~31;
    if (k0 >= kendB) return;

    const int tid = threadIdx.x;
    const int n_in = (tid & 15) * 4, k_in = tid >> 4;
    const float* src = value + ((size_t)b * 1024 + k0 + k_in) * 512 + n0 + n_in;
    #pragma unroll
    for (int p = 0; p < 4; ++p) {
        const float4 x = *(const float4*)(src + (size_t)p * 16 * 512);
        t[k_in + p * 16][n_in + 0] = x.x;
        t[k_in + p * 16][n_in + 1] = x.y;
        t[k_in + p * 16][n_in + 2] = x.z;
        t[k_in + p * 16][n_in + 3] = x.w;
    }
    __syncthreads();

    const int rn = tid >> 2, c0 = (tid & 3) * 16;
    uint hp[8], lp[8];
    #pragma unroll
    for (int i = 0; i < 8; ++i)
        hp[i] = pack_hi_lo(t[c0 + 2 * i][rn], t[c0 + 2 * i + 1][rn], lp[i]);
    const size_t off = ((size_t)b * 512 + n0 + rn) * 1024 + k0 + c0;
    *(uint4*)(VT_hi + off) = make_uint4(hp[0], hp[1], hp[2], hp[3]);
    *(uint4*)(VT_hi + off + 8) = make_uint4(hp[4], hp[5], hp[6], hp[7]);
    *(uint4*)(VT_lo + off) = make_uint4(lp[0], lp[1], lp[2], lp[3]);
    *(uint4*)(VT_lo + off + 8) = make_uint4(lp[4], lp[5], lp[6], lp[7]);
}

// ---------------------------------------------------------------------------
// Kernel P (MFMA): proj via 3-MFMA hi/lo bf16. A loaded f32 + in-register
// trunc-split (prep_a kernel eliminated). Wave tile 32m x 64n, K=512 by 32.
// ---------------------------------------------------------------------------
#define LOADA(s, kbase) { const int ko = (kbase) + half * 8;                   \
    _Pragma("unroll") for (int f = 0; f < 2; ++f) {                            \
        const float4 x0 = *(const float4*)(a_f + (size_t)(f * 16) * 512 + ko); \
        const float4 x1 = *(const float4*)(a_f + (size_t)(f * 16) * 512 + ko + 4); \
        split8(x0, x1, ah##s[f], al##s[f]); } }

#define LOADB(s, kbase) { const int ko = (kbase) + half * 8;                   \
    _Pragma("unroll") for (int f = 0; f < 4; ++f) {                            \
        bh##s[f] = *(const short8v*)(wt_h + (size_t)(f * 16) * 512 + ko);      \
        bl##s[f] = *(const short8v*)(wt_l + (size_t)(f * 16) * 512 + ko); } }

#define MFMAS(s)                                                                          \
    _Pragma("unroll") for (int mf = 0; mf < 2; ++mf)                                      \
    _Pragma("unroll") for (int nf = 0; nf < 4; ++nf) {                                    \
        acc[mf][nf] = __builtin_amdgcn_mfma_f32_16x16x32_bf16(ah##s[mf], bh##s[nf], acc[mf][nf], 0, 0, 0); \
        acc[mf][nf] = __builtin_amdgcn_mfma_f32_16x16x32_bf16(ah##s[mf], bl##s[nf], acc[mf][nf], 0, 0, 0); \
        acc[mf][nf] = __builtin_amdgcn_mfma_f32_16x16x32_bf16(al##s[mf], bh##s[nf], acc[mf][nf], 0, 0, 0); }

__global__ __launch_bounds__(64) void proj_mfma(
    const float* __restrict__ query, const float* __restrict__ key,
    const ushort* __restrict__ WT_hi, const ushort* __restrict__ WT_lo,
    const int* __restrict__ valid_len,
    float* __restrict__ EqT, float* __restrict__ EkT)
{
    const int lane = threadIdx.x;
    const int n0 = blockIdx.x * 64;
    const int m0 = blockIdx.y * 32;
    const bool isq = (m0 < 1024);
    int b = 0, kk0 = 0;
    if (!isq) {
        kk0 = (m0 - 1024) & 1023;
        b = (m0 - 1024) >> 10;
        if (kk0 >= valid_len[b]) return;
    }
    const int r = lane & 15, half = lane >> 4;
    const size_t wsel = isq ? 0 : (size_t)256 * 512;
    const ushort* wt_h = WT_hi + wsel + (size_t)(n0 + r) * 512;
    const ushort* wt_l = WT_lo + wsel + (size_t)(n0 + r) * 512;
    const float* a_f = isq ? (query + (size_t)(m0 + r) * 512)
                           : (key + (size_t)(m0 - 1024 + r) * 512);

    float4v acc[2][4] = {{{0.f}}};
    short8v ah0[2], al0[2], bh0[4], bl0[4];
    short8v ah1[2], al1[2], bh1[4], bl1[4];

    LOADA(0, 0); LOADB(0, 0);
    for (int kt = 0; kt < 512; kt += 64) {
        LOADA(1, kt + 32); LOADB(1, kt + 32);
        MFMAS(0);
        if (kt + 64 < 512) { LOADA(0, kt + 64); LOADB(0, kt + 64); }
        MFMAS(1);
    }

    #pragma unroll
    for (int mf = 0; mf < 2; ++mf) {
        #pragma unroll
        for (int nf = 0; nf < 4; ++nf) {
            float4v e;
            #pragma unroll
            for (int i = 0; i < 4; ++i)
                e[i] = __builtin_amdgcn_exp2f(acc[mf][nf][i] * TWO_LOG2E);
            if (isq) {
                *(float4v*)(EqT + (size_t)(n0 + nf * 16 + r) * 1024 +
                            m0 + mf * 16 + half * 4) = e;
            } else {
                *(float4v*)(EkT + (size_t)(b * 256 + n0 + nf * 16 + r) * 1024 +
                            kk0 + mf * 16 + half * 4) = e;
            }
        }
    }
}

// ---------------------------------------------------------------------------
// Score pass A: P[b*256+q][k] = -2 * sum_h wv[h]*rcp(Eq*Ek+1).
// Block = (b, 8q, 256k): 1024 thr = (hq 0..3) x (kl 0..255); each thread does
// 8q x 64h, then LDS-reduce across the 4 h-quarters -> single P buffer.
// 512 blocks x 16 waves = 32 waves/CU (full occupancy). XCD-chunked swizzle
// co-locates the 32 q-blocks sharing one EkT (b,kt) slice (256 KB, L2-fits).
// ---------------------------------------------------------------------------
__global__ __launch_bounds__(1024) void score_partial(
    const float* __restrict__ EqT, const float* __restrict__ EkT,
    const float* __restrict__ wv, const int* __restrict__ valid_len,
    float* __restrict__ P)
{
    __shared__ float eqs[256][8];      // 8 KB
    __shared__ float wvs[256];         // 1 KB
    __shared__ float part[4][8][256];  // 32 KB

    const int orig = blockIdx.x;                 // 512
    const int wgid = (orig & 7) * 64 + (orig >> 3);   // chunk-64 per XCD
    const int qg = wgid & 31;
    const int rest = wgid >> 5;                  // 16 = 4 kt x 4 b
    const int kt = rest & 3;
    const int b = rest >> 2;

    const int vlen = valid_len[b];
    if (kt * 256 >= vlen) return;                // whole tile masked

    const int tid = threadIdx.x;
    const int hq = tid >> 8, kl = tid & 255;
    const int k = kt * 256 + kl;
    const int q0 = qg * 8;

    if (tid < 256) wvs[tid] = wv[tid];
    {
        const int i0 = tid * 2;
        const int h = i0 >> 3, q = i0 & 7;
        const float* ep = EqT + (size_t)h * 1024 + b * 256 + q0 + q;
        eqs[h][q] = ep[0];
        eqs[h][q + 1] = ep[1];
    }
    __syncthreads();

    float acc[8] = {};
    if (k < vlen) {
        const float* ekp = EkT + (size_t)(b * 256 + hq * 64) * 1024 + k;
        #pragma unroll 2
        for (int h = 0; h < 64; ++h) {
            const float ek = ekp[(size_t)h * 1024];
            const float w = wvs[hq * 64 + h];
            const float4 e0 = *(const float4*)&eqs[hq * 64 + h][0];
            const float4 e1 = *(const float4*)&eqs[hq * 64 + h][4];
            acc[0] = fmaf(w, __builtin_amdgcn_rcpf(fmaf(e0.x, ek, 1.f)), acc[0]);
            acc[1] = fmaf(w, __builtin_amdgcn_rcpf(fmaf(e0.y, ek, 1.f)), acc[1]);
            acc[2] = fmaf(w, __builtin_amdgcn_rcpf(fmaf(e0.z, ek, 1.f)), acc[2]);
            acc[3] = fmaf(w, __builtin_amdgcn_rcpf(fmaf(e0.w, ek, 1.f)), acc[3]);
            acc[4] = fmaf(w, __builtin_amdgcn_rcpf(fmaf(e1.x, ek, 1.f)), acc[4]);
            acc[5] = fmaf(w, __builtin_amdgcn_rcpf(fmaf(e1.y, ek, 1.f)), acc[5]);
            acc[6] = fmaf(w, __builtin_amdgcn_rcpf(fmaf(e1.z, ek, 1.f)), acc[6]);
            acc[7] = fmaf(w, __builtin_amdgcn_rcpf(fmaf(e1.w, ek, 1.f)), acc[7]);
        }
    }

    #pragma unroll
    for (int q = 0; q < 8; ++q) part[hq][q][kl] = acc[q];
    __syncthreads();

    #pragma unroll
    for (int j = 0; j < 2; ++j) {
        const int q = hq * 2 + j;
        const float s = part[0][q][kl] + part[1][q][kl] +
                        part[2][q][kl] + part[3][q][kl];
        P[(size_t)(b * 256 + q0 + q) * 1024 + k] = -2.f * s;
    }
}

// ---------------------------------------------------------------------------
// Score pass B: masked softmax over P; bf16 hi/lo attn output.
// Block = (b, 4q); 1024 threads; thread owns k = tid.
// ---------------------------------------------------------------------------
__global__ __launch_bounds__(1024) void softmax_kernel(
    const float* __restrict__ P, const int* __restrict__ valid_len,
    ushort* __restrict__ attn_hi, ushort* __restrict__ attn_lo)
{
    __shared__ float red[16][4];

    const int tid = threadIdx.x;
    const int b = blockIdx.x >> 6;
    const int q0 = (blockIdx.x & 63) << 2;

    const int vlen = valid_len[b];
    const int k = tid;
    const bool v = (k < vlen);

    float s[4], m[4];
    #pragma unroll
    for (int q = 0; q < 4; ++q) {
        s[q] = P[(size_t)(b * 256 + q0 + q) * 1024 + k];
        m[q] = v ? s[q] : -1e30f;
    }
    #pragma unroll
    for (int o = 32; o; o >>= 1) {
        #pragma unroll
        for (int q = 0; q < 4; ++q) m[q] = fmaxf(m[q], __shfl_xor(m[q], o));
    }
    const int wid = tid >> 6;
    if ((tid & 63) == 0) {
        #pragma unroll
        for (int q = 0; q < 4; ++q) red[wid][q] = m[q];
    }
    __syncthreads();
    #pragma unroll
    for (int q = 0; q < 4; ++q) {
        float mm = red[0][q];
        #pragma unroll
        for (int w = 1; w < 16; ++w) mm = fmaxf(mm, red[w][q]);
        m[q] = mm;
    }
    __syncthreads();

    float p[4], l[4];
    #pragma unroll
    for (int q = 0; q < 4; ++q) {
        p[q] = v ? __builtin_amdgcn_exp2f((s[q] - m[q]) * LOG2E) : 0.f;
        l[q] = p[q];
    }
    #pragma unroll
    for (int o = 32; o; o >>= 1) {
        #pragma unroll
        for (int q = 0; q < 4; ++q) l[q] += __shfl_xor(l[q], o);
    }
    if ((tid & 63) == 0) {
        #pragma unroll
        for (int q = 0; q < 4; ++q) red[wid][q] = l[q];
    }
    __syncthreads();
    #pragma unroll
    for (int q = 0; q < 4; ++q) {
        float ss = red[0][q];
        #pragma unroll
        for (int w = 1; w < 16; ++w) ss += red[w][q];
        const float a = p[q] * __builtin_amdgcn_rcpf(ss);
        const uint hi = rne_bf16(a);
        const float lo = a - __uint_as_float(hi << 16);
        const size_t off = (size_t)(b * 256 + q0 + q) * 1024 + k;
        attn_hi[off] = (ushort)hi;
        attn_lo[off] = (ushort)rne_bf16(lo);
    }
}

// ---------------------------------------------------------------------------
// Kernel D (MFMA): out = attn @ value, 3-MFMA hi/lo. 4-wave blocks: the 4
// waves cover q0..q0+63 over the SAME 32-n VT slice (VT traffic /4), with
// XCD-chunked swizzle co-locating the 4 q-blocks per (n,b) on one XCD L2.
// grid 256 x 256 thr; per-wave tile 16q x 32n; K bounded by ceil(vlen/32).
// ---------------------------------------------------------------------------
#define PVLOAD(s, ko) {                                   \
    ah##s = *(const short8v*)(ah_p + (ko));               \
    al##s = *(const short8v*)(al_p + (ko));               \
    bh0##s = *(const short8v*)(bh_p + (ko));              \
    bl0##s = *(const short8v*)(bl_p + (ko));              \
    bh1##s = *(const short8v*)(bh_p + 16 * 1024 + (ko));  \
    bl1##s = *(const short8v*)(bl_p + 16 * 1024 + (ko)); }

#define PVMFMA(s) {                                                              \
    acc0 = __builtin_amdgcn_mfma_f32_16x16x32_bf16(ah##s, bh0##s, acc0, 0, 0, 0); \
    acc0 = __builtin_amdgcn_mfma_f32_16x16x32_bf16(ah##s, bl0##s, acc0, 0, 0, 0); \
    acc0 = __builtin_amdgcn_mfma_f32_16x16x32_bf16(al##s, bh0##s, acc0, 0, 0, 0); \
    acc1 = __builtin_amdgcn_mfma_f32_16x16x32_bf16(ah##s, bh1##s, acc1, 0, 0, 0); \
    acc1 = __builtin_amdgcn_mfma_f32_16x16x32_bf16(ah##s, bl1##s, acc1, 0, 0, 0); \
    acc1 = __builtin_amdgcn_mfma_f32_16x16x32_bf16(al##s, bh1##s, acc1, 0, 0, 0); }

__global__ __launch_bounds__(256) void pv_mfma(
    const ushort* __restrict__ attn_hi, const ushort* __restrict__ attn_lo,
    const ushort* __restrict__ VT_hi, const ushort* __restrict__ VT_lo,
    const int* __restrict__ valid_len,
    float* __restrict__ out)
{
    const int orig = blockIdx.x;                 // 256
    const int wgid = (orig & 7) * 32 + (orig >> 3);   // chunk-32 per XCD
    const int qb = wgid & 3;
    const int rest = wgid >> 2;                  // 64 = 4 b x 16 n
    const int b = rest & 3;
    const int nt = rest >> 2;

    const int wid = threadIdx.x >> 6, lane = threadIdx.x & 63;
    const int n0 = nt * 32;
    const int q0 = qb * 64 + wid * 16;
    const int r = lane & 15, half = lane >> 4;
    const int kend = (valid_len[b] + 31) & ~31;

    const ushort* ah_p = attn_hi + (size_t)(b * 256 + q0 + r) * 1024 + half * 8;
    const ushort* al_p = attn_lo + (size_t)(b * 256 + q0 + r) * 1024 + half * 8;
    const ushort* bh_p = VT_hi + (size_t)(b * 512 + n0 + r) * 1024 + half * 8;
    const ushort* bl_p = VT_lo + (size_t)(b * 512 + n0 + r) * 1024 + half * 8;

    float4v acc0 = {0.f}, acc1 = {0.f};
    short8v ah0, al0, bh00, bl00, bh10, bl10;
    short8v ah1, al1, bh01, bl01, bh11, bl11;

    PVLOAD(0, 0);
    for (int kt = 0; kt < kend; kt += 64) {
        if (kt + 32 < kend) PVLOAD(1, kt + 32);
        PVMFMA(0);
        if (kt + 64 < kend) PVLOAD(0, kt + 64);
        if (kt + 32 < kend) PVMFMA(1);
    }

    float* op = out + (size_t)b * 256 * 512 + (size_t)(q0 + half * 4) * 512 + n0 + r;
    #pragma unroll
    for (int i = 0; i < 4; ++i) {
        op[(size_t)i * 512] = acc0[i];
        op[(size_t)i * 512 + 16] = acc1[i];
    }
}

// ---------------------------------------------------------------------------
extern "C" void kernel_launch(void* const* d_in, const int* in_sizes, int n_in,
                              void* d_out, int out_size, void* d_ws, size_t ws_size,
                              hipStream_t stream)
{
    const float* query = (const float*)d_in[0];   // [4,256,512]
    const float* key   = (const float*)d_in[1];   // [4,1024,512]
    const float* value = (const float*)d_in[2];   // [4,1024,512]
    const int*   vlen  = (const int*)d_in[3];     // [4]
    const float* Wq    = (const float*)d_in[4];   // [512,256]
    const float* Wk    = (const float*)d_in[5];   // [512,256]
    const float* wv    = (const float*)d_in[6];   // [256]
    float* out = (float*)d_out;                   // [4,256,512]

    float*  EqT     = (float*)d_ws;               // [256][1024]    = 262144 f
    float*  EkT     = EqT + 262144;               // [4][256][1024] = 1048576 f
    float*  P       = EkT + 1048576;              // [1024][1024]   = 1048576 f
    ushort* WT_hi   = (ushort*)(P + 1048576);     // [2][256][512]
    ushort* WT_lo   = WT_hi + 262144;
    ushort* attn_hi = WT_lo + 262144;             // [1024][1024]
    ushort* attn_lo = attn_hi + 1048576;
    ushort* VT_hi   = attn_lo + 1048576;          // [4][512][1024]
    ushort* VT_lo   = VT_hi + 2097152;

    hipLaunchKernelGGL(prep_w, dim3(128), dim3(256), 0, stream,
                       Wq, Wk, WT_hi, WT_lo);
    hipLaunchKernelGGL(prep_v, dim3(8, 16, 4), dim3(256), 0, stream,
                       value, vlen, VT_hi, VT_lo);
    hipLaunchKernelGGL(proj_mfma, dim3(4, 160), dim3(64), 0, stream,
                       query, key, WT_hi, WT_lo, vlen, EqT, EkT);
    hipLaunchKernelGGL(score_partial, dim3(512), dim3(1024), 0, stream,
                       EqT, EkT, wv, vlen, P);
    hipLaunchKernelGGL(softmax_kernel, dim3(256), dim3(1024), 0, stream,
                       P, vlen, attn_hi, attn_lo);
    hipLaunchKernelGGL(pv_mfma, dim3(256), dim3(256), 0, stream,
                       attn_hi, attn_lo, VT_hi, VT_lo, vlen, out);
}